// Round 10
// baseline (378.128 us; speedup 1.0000x reference)
//
#include <hip/hip_runtime.h>
#include <cstdint>
#include <cstddef>

#define DDIM 200
#define KPAD 224          // DDIM padded to 7*32 for K2
#define BATCH 512
#define NENT 100000
#define KFLAT 40000       // 200*200 flattened (i,j)
#define SPLIT 50          // K1 split-K chunks; each = 4 i-values = 800 flat-K rows
#define CHUNK_K 800
#define K1_BM 64
#define E1P 216           // e1_s row stride u16: 432B = 16B-aligned, 2-way banks
#define K2_TN 256         // K2 block entity width -> 1KB per wave-store
#define TS_W 268          // K2 epilogue transpose row stride (f32): 1072B, 16B-aligned

typedef __attribute__((ext_vector_type(8))) short bf16x8;
typedef __attribute__((ext_vector_type(4))) float f32x4;
typedef __attribute__((ext_vector_type(4))) unsigned short u16x4;
typedef unsigned short u16;

__device__ inline u16 f2bf(float f) {
    union { float f; uint32_t u; } v; v.f = f;
    uint32_t u = v.u;
    u += 0x7FFFu + ((u >> 16) & 1u);
    return (u16)(u >> 16);
}
__device__ inline float bf2f(u16 b) {
    union { uint32_t u; float f; } v; v.u = ((uint32_t)b) << 16;
    return v.f;
}

// ---------------------------------------------------------------------------
// Kernel 0: W [40000][200] f32  ->  Wt [200][40000] bf16 (transposed, bf16).
// ---------------------------------------------------------------------------
__global__ __launch_bounds__(256) void transpose_w_bf16(
    const float* __restrict__ W, u16* __restrict__ Wt)
{
    __shared__ u16 T[DDIM][72];            // 28.8 KB, row stride 144B (16-aligned)
    const int tid = threadIdx.x;
    const int ij0 = blockIdx.x * 64;

    for (int l = tid; l < 64 * 50; l += 256) {
        int m = l & 63, c4 = l >> 6;       // m: ij within tile, c4: f32x4 group of n
        f32x4 v = *(const f32x4*)&W[(size_t)(ij0 + m) * DDIM + c4 * 4];
        #pragma unroll
        for (int q = 0; q < 4; ++q) T[c4 * 4 + q][m] = f2bf(v[q]);
    }
    __syncthreads();
    for (int l = tid; l < DDIM * 8; l += 256) {
        int n = l >> 3, g = l & 7;
        *(bf16x8*)&Wt[(size_t)n * KFLAT + ij0 + g * 8] =
            *(const bf16x8*)&T[n][g * 8];
    }
}

// ---------------------------------------------------------------------------
// Kernel 1 (R8-proven): split-K MFMA GEMM
// x[b,k] = sum_ij (r[b,i]*e1[b,j]) W[ij,k]; vectorized A-gen.
// ---------------------------------------------------------------------------
__global__ __launch_bounds__(256) void tucker_x_partial(
    const int* __restrict__ X, const float* __restrict__ E1,
    const float* __restrict__ R, const u16* __restrict__ Wt,
    float* __restrict__ x_part)
{
    __shared__ u16   e1_s[K1_BM][E1P];      // bf16 e1 rows, stride 216 (432B)
    __shared__ float r_s[K1_BM][4];         // fp32 r values for chunk's 4 i's
    __shared__ u16   At[K1_BM][40];         // A tile 64x32 bf16 (pad 40)
    __shared__ u16   Bt[208][40];           // B^T tile 200x32 bf16

    const int tid = threadIdx.x;
    const int b0 = blockIdx.x * K1_BM;
    const int chunk = blockIdx.y;
    const int i0 = chunk * 4;
    const int kflat0 = chunk * CHUNK_K;

    for (int l = tid; l < K1_BM * 50; l += 256) {
        int m = l / 50, c4 = l - (l / 50) * 50;
        int subj = X[(b0 + m) * 2 + 0];
        f32x4 v = *(const f32x4*)&E1[(size_t)subj * DDIM + c4 * 4];
        u16x4 b;
        b[0] = f2bf(v[0]); b[1] = f2bf(v[1]); b[2] = f2bf(v[2]); b[3] = f2bf(v[3]);
        *(u16x4*)&e1_s[m][c4 * 4] = b;
    }
    if (tid < K1_BM * 4) {
        int m = tid >> 2, q = tid & 3;
        int rel = X[(b0 + m) * 2 + 1];
        r_s[m][q] = R[(size_t)rel * DDIM + i0 + q];
    }
    for (int l = tid; l < 8 * 40; l += 256)   // zero pad rows (n = 200..207)
        Bt[200 + l / 40][l % 40] = 0;

    const int wid = tid >> 6, lane = tid & 63;
    const int lr = lane & 15, lq = lane >> 4;

    f32x4 acc[13];
    #pragma unroll
    for (int f = 0; f < 13; ++f)
        #pragma unroll
        for (int q = 0; q < 4; ++q) acc[f][q] = 0.f;

    for (int s = 0; s < CHUNK_K / 32; ++s) {           // 25 K-steps
        __syncthreads();
        // --- stage A tile (64x32): 1 b128 read + 8 fma/cvt + 1 b128 write
        {
            int m = tid >> 2, kb = (tid & 3) * 8;
            int base = s * 32 + kb;                    // multiple of 8, 0..792
            int io = base / DDIM;                      // constant over group
            int j0 = base - io * DDIM;                 // mult of 8, <=192
            float rv = r_s[m][io];
            bf16x8 ev = *(const bf16x8*)&e1_s[m][j0];
            bf16x8 av;
            #pragma unroll
            for (int e = 0; e < 8; ++e)
                av[e] = (short)f2bf(rv * bf2f((u16)ev[e]));
            *(bf16x8*)&At[m][kb] = av;
        }
        // --- stage B^T from Wt: pure bf16x8 copies, coalesced + conflict-free
        for (int l = tid; l < DDIM * 4; l += 256) {
            int n = l >> 2, g = l & 3;
            *(bf16x8*)&Bt[n][g * 8] =
                *(const bf16x8*)&Wt[(size_t)n * KFLAT + kflat0 + s * 32 + g * 8];
        }
        __syncthreads();
        bf16x8 af = *(const bf16x8*)&At[wid * 16 + lr][lq * 8];
        #pragma unroll
        for (int f = 0; f < 13; ++f) {
            bf16x8 bfr = *(const bf16x8*)&Bt[f * 16 + lr][lq * 8];
            acc[f] = __builtin_amdgcn_mfma_f32_16x16x32_bf16(af, bfr, acc[f], 0, 0, 0);
        }
    }

    float* dst = x_part + ((size_t)chunk * BATCH + b0) * DDIM;
    #pragma unroll
    for (int f = 0; f < 13; ++f) {
        int n = f * 16 + lr;
        if (n < DDIM) {
            #pragma unroll
            for (int r4 = 0; r4 < 4; ++r4) {
                int m = wid * 16 + lq * 4 + r4;
                dst[(size_t)m * DDIM + n] = acc[f][r4];
            }
        }
    }
}

// ---------------------------------------------------------------------------
// Kernel 1b: deterministic reduction of partials -> bf16 x, padded [512][224]
// ---------------------------------------------------------------------------
__global__ __launch_bounds__(256) void reduce_x(
    const float* __restrict__ part, u16* __restrict__ xbf)
{
    int id = blockIdx.x * 256 + threadIdx.x;
    if (id < BATCH * KPAD) {
        int b = id / KPAD, c = id - (id / KPAD) * KPAD;
        float s = 0.f;
        if (c < DDIM) {
            #pragma unroll 10
            for (int ch = 0; ch < SPLIT; ++ch)
                s += part[(size_t)ch * BATCH * DDIM + b * DDIM + c];
        }
        xbf[id] = f2bf(s);
    }
}

// ---------------------------------------------------------------------------
// Kernel 2 (R10): out = sigmoid(x @ E2^T). Block = ALL 512 rows x 256 ents,
// 1024 thr (16 waves, wave = 64 rows x 128 ents, acc[4][8] = 128 regs).
// Theory: every prior k2 emitted wave-stores covering only 256B of one out
// row (MFMA fragment shape leaked into the store shape); fillBuffer's 1KB-
// contiguous wave-stores hit 26.7 GB/s/CU vs our 6.7 -- exactly 4x = the
// contiguity ratio. Here the epilogue gathers so ONE wave-store = ONE row x
// 256 ents = 1KB contiguous nontemporal dwordx4.
//  - E2 panel (256 ents x 224 bf16, 118.8KB LDS) staged ONCE -> E2 fetched
//    once total (no R5/R7 re-fetch confound). 1 block/CU; R6 proved k2 is
//    insensitive to occupancy.
//  - barrier-free k-loop; af from L2-resident xbf.
//  - epilogue: 8 chunk-phases of 64 rows through Ts[64][268] (aliases dead
//    B panel): owner m-group scatters acc, barrier, all 16 waves store
//    4 rows each as single 1KB nt stores.
// ---------------------------------------------------------------------------
__global__ __launch_bounds__(1024) void logits_sigmoid_mfma(
    const u16* __restrict__ xbf, const float* __restrict__ E2,
    float* __restrict__ out)
{
    __shared__ __align__(16) unsigned char pool[K2_TN * 232 * 2]; // 118,784 B
    u16   (*Bs)[232]  = (u16 (*)[232])pool;    // 256 x 232 bf16
    float (*Ts)[TS_W] = (float (*)[TS_W])pool; // 64 x 268 f32 = 68.6KB (alias)

    const int tid = threadIdx.x;
    const int n0 = blockIdx.x * K2_TN;
    const int wid = tid >> 6, lane = tid & 63;
    const int mg = wid >> 1, ng = wid & 1;     // 8 m-groups x 2 n-groups
    const int lr = lane & 15, lq = lane >> 4;

    // ---- stage B panel: 256 ents x 200 cols f32 -> bf16 (cols 200..223 = 0)
    for (int l = tid; l < K2_TN * 28; l += 1024) {   // 28 groups of 8 cols
        int row = l / 28, g = l - (l / 28) * 28;
        int gn = n0 + row;
        u16x4 a4; a4[0] = 0; a4[1] = 0; a4[2] = 0; a4[3] = 0;
        u16x4 b4; b4[0] = 0; b4[1] = 0; b4[2] = 0; b4[3] = 0;
        if (g < 25 && gn < NENT) {                   // 25*8 = 200 cols exactly
            f32x4 v0 = *(const f32x4*)&E2[(size_t)gn * DDIM + g * 8];
            f32x4 v1 = *(const f32x4*)&E2[(size_t)gn * DDIM + g * 8 + 4];
            a4[0] = f2bf(v0[0]); a4[1] = f2bf(v0[1]);
            a4[2] = f2bf(v0[2]); a4[3] = f2bf(v0[3]);
            b4[0] = f2bf(v1[0]); b4[1] = f2bf(v1[1]);
            b4[2] = f2bf(v1[2]); b4[3] = f2bf(v1[3]);
        }
        *(u16x4*)&Bs[row][g * 8]     = a4;
        *(u16x4*)&Bs[row][g * 8 + 4] = b4;
    }
    __syncthreads();                 // B panel ready

    f32x4 acc[4][8];
    #pragma unroll
    for (int fm = 0; fm < 4; ++fm)
        #pragma unroll
        for (int fn = 0; fn < 8; ++fn)
            #pragma unroll
            for (int q = 0; q < 4; ++q) acc[fm][fn][q] = 0.f;

    #pragma unroll
    for (int s = 0; s < 7; ++s) {    // barrier-free k-loop
        bf16x8 af[4];
        #pragma unroll
        for (int fm = 0; fm < 4; ++fm) {
            int row = mg * 64 + fm * 16 + lr;        // 0..511
            af[fm] = *(const bf16x8*)&xbf[row * KPAD + s * 32 + lq * 8];
        }
        bf16x8 bfr[8];
        #pragma unroll
        for (int fn = 0; fn < 8; ++fn)
            bfr[fn] = *(const bf16x8*)&Bs[ng * 128 + fn * 16 + lr][s * 32 + lq * 8];
        #pragma unroll
        for (int fm = 0; fm < 4; ++fm)
            #pragma unroll
            for (int fn = 0; fn < 8; ++fn)
                acc[fm][fn] = __builtin_amdgcn_mfma_f32_16x16x32_bf16(
                    af[fm], bfr[fn], acc[fm][fn], 0, 0, 0);
    }

    // ---- epilogue: 8 phases x 64-row chunks; 1KB-contiguous nt stores
    for (int c = 0; c < 8; ++c) {
        __syncthreads();             // prev gather done (c=0: k-loop done)
        if (mg == c) {               // owner waves (2c, 2c+1) scatter
            #pragma unroll
            for (int fm = 0; fm < 4; ++fm)
                #pragma unroll
                for (int fn = 0; fn < 8; ++fn)
                    #pragma unroll
                    for (int r4 = 0; r4 < 4; ++r4)
                        Ts[fm * 16 + lq * 4 + r4][ng * 128 + fn * 16 + lr] =
                            acc[fm][fn][r4];
        }
        __syncthreads();
        #pragma unroll
        for (int rr = 0; rr < 4; ++rr) {
            int row = wid * 4 + rr;              // 0..63 within chunk
            f32x4 v = *(const f32x4*)&Ts[row][lane * 4];
            f32x4 o;
            #pragma unroll
            for (int j = 0; j < 4; ++j)
                o[j] = __builtin_amdgcn_rcpf(1.0f + __expf(-v[j]));
            int gm = c * 64 + row;               // 0..511
            int gn = n0 + lane * 4;              // NENT % 4 == 0 -> vector-safe
            if (gn < NENT)
                __builtin_nontemporal_store(o,
                    (f32x4*)&out[(size_t)gm * NENT + gn]);
        }
    }
}

extern "C" void kernel_launch(void* const* d_in, const int* in_sizes, int n_in,
                              void* d_out, int out_size, void* d_ws, size_t ws_size,
                              hipStream_t stream) {
    const int*   X  = (const int*)d_in[0];
    const float* E1 = (const float*)d_in[1];
    const float* R  = (const float*)d_in[2];
    const float* E2 = (const float*)d_in[3];
    const float* W  = (const float*)d_in[4];
    float* out = (float*)d_out;

    // workspace layout (all 16B-aligned):
    //   x_part : 50*512*200 f32 = 20,480,000 B
    //   xbf    : 512*224 u16    =    229,376 B
    //   Wt     : 200*40000 u16  = 16,000,000 B
    float* x_part = (float*)d_ws;
    u16*   xbf    = (u16*)(x_part + (size_t)SPLIT * BATCH * DDIM);
    u16*   Wt     = xbf + (size_t)BATCH * KPAD;

    transpose_w_bf16<<<KFLAT / 64, 256, 0, stream>>>(W, Wt);
    tucker_x_partial<<<dim3(BATCH / K1_BM, SPLIT), 256, 0, stream>>>(
        X, E1, R, Wt, x_part);
    reduce_x<<<dim3((BATCH * KPAD + 255) / 256), 256, 0, stream>>>(x_part, xbf);
    logits_sigmoid_mfma<<<(NENT + K2_TN - 1) / K2_TN, 1024, 0, stream>>>(
        xbf, E2, out);
}

// Round 11
// 156.020 us; speedup vs baseline: 2.4236x; 2.4236x over previous
//
#include <hip/hip_runtime.h>
#include <cstdint>
#include <cstddef>

#define DDIM 200
#define KPAD 224          // DDIM padded to 7*32 for K2
#define BATCH 512
#define NENT 100000
#define KFLAT 40000       // 200*200 flattened (i,j)
#define SPLIT 50          // K1 split-K chunks; each = 4 i-values = 800 flat-K rows
#define CHUNK_K 800
#define K1_BM 64
#define E1P 216           // e1_s row stride u16: 432B = 16B-aligned, 2-way banks
#define K2_BM 256         // K2 block rows (grid.y = 2 -> E2 staged only 2x)
#define K2_BN 256         // K2 block ents -> 1KB contiguous per wave-store
#define TS_W 260          // K2 epilogue transpose row stride (f32)

typedef __attribute__((ext_vector_type(8))) short bf16x8;
typedef __attribute__((ext_vector_type(4))) float f32x4;
typedef __attribute__((ext_vector_type(4))) unsigned short u16x4;
typedef unsigned short u16;

__device__ inline u16 f2bf(float f) {
    union { float f; uint32_t u; } v; v.f = f;
    uint32_t u = v.u;
    u += 0x7FFFu + ((u >> 16) & 1u);
    return (u16)(u >> 16);
}
__device__ inline float bf2f(u16 b) {
    union { uint32_t u; float f; } v; v.u = ((uint32_t)b) << 16;
    return v.f;
}

// ---------------------------------------------------------------------------
// Kernel 0: W [40000][200] f32  ->  Wt [200][40000] bf16 (transposed, bf16).
// ---------------------------------------------------------------------------
__global__ __launch_bounds__(256) void transpose_w_bf16(
    const float* __restrict__ W, u16* __restrict__ Wt)
{
    __shared__ u16 T[DDIM][72];            // 28.8 KB, row stride 144B (16-aligned)
    const int tid = threadIdx.x;
    const int ij0 = blockIdx.x * 64;

    for (int l = tid; l < 64 * 50; l += 256) {
        int m = l & 63, c4 = l >> 6;       // m: ij within tile, c4: f32x4 group of n
        f32x4 v = *(const f32x4*)&W[(size_t)(ij0 + m) * DDIM + c4 * 4];
        #pragma unroll
        for (int q = 0; q < 4; ++q) T[c4 * 4 + q][m] = f2bf(v[q]);
    }
    __syncthreads();
    for (int l = tid; l < DDIM * 8; l += 256) {
        int n = l >> 3, g = l & 7;
        *(bf16x8*)&Wt[(size_t)n * KFLAT + ij0 + g * 8] =
            *(const bf16x8*)&T[n][g * 8];
    }
}

// ---------------------------------------------------------------------------
// Kernel 1 (R8-proven): split-K MFMA GEMM
// x[b,k] = sum_ij (r[b,i]*e1[b,j]) W[ij,k]; vectorized A-gen.
// ---------------------------------------------------------------------------
__global__ __launch_bounds__(256) void tucker_x_partial(
    const int* __restrict__ X, const float* __restrict__ E1,
    const float* __restrict__ R, const u16* __restrict__ Wt,
    float* __restrict__ x_part)
{
    __shared__ u16   e1_s[K1_BM][E1P];      // bf16 e1 rows, stride 216 (432B)
    __shared__ float r_s[K1_BM][4];         // fp32 r values for chunk's 4 i's
    __shared__ u16   At[K1_BM][40];         // A tile 64x32 bf16 (pad 40)
    __shared__ u16   Bt[208][40];           // B^T tile 200x32 bf16

    const int tid = threadIdx.x;
    const int b0 = blockIdx.x * K1_BM;
    const int chunk = blockIdx.y;
    const int i0 = chunk * 4;
    const int kflat0 = chunk * CHUNK_K;

    for (int l = tid; l < K1_BM * 50; l += 256) {
        int m = l / 50, c4 = l - (l / 50) * 50;
        int subj = X[(b0 + m) * 2 + 0];
        f32x4 v = *(const f32x4*)&E1[(size_t)subj * DDIM + c4 * 4];
        u16x4 b;
        b[0] = f2bf(v[0]); b[1] = f2bf(v[1]); b[2] = f2bf(v[2]); b[3] = f2bf(v[3]);
        *(u16x4*)&e1_s[m][c4 * 4] = b;
    }
    if (tid < K1_BM * 4) {
        int m = tid >> 2, q = tid & 3;
        int rel = X[(b0 + m) * 2 + 1];
        r_s[m][q] = R[(size_t)rel * DDIM + i0 + q];
    }
    for (int l = tid; l < 8 * 40; l += 256)   // zero pad rows (n = 200..207)
        Bt[200 + l / 40][l % 40] = 0;

    const int wid = tid >> 6, lane = tid & 63;
    const int lr = lane & 15, lq = lane >> 4;

    f32x4 acc[13];
    #pragma unroll
    for (int f = 0; f < 13; ++f)
        #pragma unroll
        for (int q = 0; q < 4; ++q) acc[f][q] = 0.f;

    for (int s = 0; s < CHUNK_K / 32; ++s) {           // 25 K-steps
        __syncthreads();
        // --- stage A tile (64x32): 1 b128 read + 8 fma/cvt + 1 b128 write
        {
            int m = tid >> 2, kb = (tid & 3) * 8;
            int base = s * 32 + kb;                    // multiple of 8, 0..792
            int io = base / DDIM;                      // constant over group
            int j0 = base - io * DDIM;                 // mult of 8, <=192
            float rv = r_s[m][io];
            bf16x8 ev = *(const bf16x8*)&e1_s[m][j0];
            bf16x8 av;
            #pragma unroll
            for (int e = 0; e < 8; ++e)
                av[e] = (short)f2bf(rv * bf2f((u16)ev[e]));
            *(bf16x8*)&At[m][kb] = av;
        }
        // --- stage B^T from Wt: pure bf16x8 copies, coalesced + conflict-free
        for (int l = tid; l < DDIM * 4; l += 256) {
            int n = l >> 2, g = l & 3;
            *(bf16x8*)&Bt[n][g * 8] =
                *(const bf16x8*)&Wt[(size_t)n * KFLAT + kflat0 + s * 32 + g * 8];
        }
        __syncthreads();
        bf16x8 af = *(const bf16x8*)&At[wid * 16 + lr][lq * 8];
        #pragma unroll
        for (int f = 0; f < 13; ++f) {
            bf16x8 bfr = *(const bf16x8*)&Bt[f * 16 + lr][lq * 8];
            acc[f] = __builtin_amdgcn_mfma_f32_16x16x32_bf16(af, bfr, acc[f], 0, 0, 0);
        }
    }

    float* dst = x_part + ((size_t)chunk * BATCH + b0) * DDIM;
    #pragma unroll
    for (int f = 0; f < 13; ++f) {
        int n = f * 16 + lr;
        if (n < DDIM) {
            #pragma unroll
            for (int r4 = 0; r4 < 4; ++r4) {
                int m = wid * 16 + lq * 4 + r4;
                dst[(size_t)m * DDIM + n] = acc[f][r4];
            }
        }
    }
}

// ---------------------------------------------------------------------------
// Kernel 1b: deterministic reduction of partials -> bf16 x, padded [512][224]
// ---------------------------------------------------------------------------
__global__ __launch_bounds__(256) void reduce_x(
    const float* __restrict__ part, u16* __restrict__ xbf)
{
    int id = blockIdx.x * 256 + threadIdx.x;
    if (id < BATCH * KPAD) {
        int b = id / KPAD, c = id - (id / KPAD) * KPAD;
        float s = 0.f;
        if (c < DDIM) {
            #pragma unroll 10
            for (int ch = 0; ch < SPLIT; ++ch)
                s += part[(size_t)ch * BATCH * DDIM + b * DDIM + c];
        }
        xbf[id] = f2bf(s);
    }
}

// ---------------------------------------------------------------------------
// Kernel 2 (R11): out = sigmoid(x @ E2^T). Block = 256 rows x 256 ents,
// 512 thr (8 waves = 2/SIMD -> 256-VGPR budget; acc[4][8]=128 regs fits,
// unlike R10's 1024-thr/64-VGPR spill). Grid = 391 x 2 (E2 staged 2x, not
// R7's 4x). THE decisive store-contiguity experiment: the epilogue's gather
// step assigns each wave ONE full output row -> a single 1KB-contiguous
// nontemporal f32x4 wave-store per row (every prior round's wave-stores
// spanned only 256B per row -- the MFMA fragment shape leaked through; the
// 4x per-CU BW gap vs fillBuffer matches that 4x contiguity gap exactly).
//  - E2 panel 256x224 bf16 (118.8KB) staged once per block; barrier-free
//    k-loop; af from L2-resident xbf.
//  - epilogue: 16 chunks of 16 rows via Ts[16][260] (aliases dead B panel):
//    owner m-group scatters acc, barrier, each wave gathers 2 rows (1024B
//    contiguous LDS read = conflict-free minimum) and nt-stores 1KB each.
// ---------------------------------------------------------------------------
__global__ __launch_bounds__(512) void logits_sigmoid_mfma(
    const u16* __restrict__ xbf, const float* __restrict__ E2,
    float* __restrict__ out)
{
    __shared__ __align__(16) unsigned char pool[K2_BN * 232 * 2]; // 118,784 B
    u16   (*Bs)[232]  = (u16 (*)[232])pool;    // 256 x 232 bf16
    float (*Ts)[TS_W] = (float (*)[TS_W])pool; // 16 x 260 f32 = 16.6KB (alias)

    const int tid = threadIdx.x;
    const int n0 = blockIdx.x * K2_BN;
    const int m0 = blockIdx.y * K2_BM;
    const int wid = tid >> 6, lane = tid & 63;
    const int mg = wid >> 1, ng = wid & 1;     // 4 m-groups x 2 n-groups
    const int lr = lane & 15, lq = lane >> 4;

    // ---- stage B panel: 256 ents x 200 cols f32 -> bf16 (cols 200..223 = 0)
    for (int l = tid; l < K2_BN * 28; l += 512) {   // 28 groups of 8 cols
        int row = l / 28, g = l - (l / 28) * 28;
        int gn = n0 + row;
        u16x4 a4; a4[0] = 0; a4[1] = 0; a4[2] = 0; a4[3] = 0;
        u16x4 b4; b4[0] = 0; b4[1] = 0; b4[2] = 0; b4[3] = 0;
        if (g < 25 && gn < NENT) {                  // 25*8 = 200 cols exactly
            f32x4 v0 = *(const f32x4*)&E2[(size_t)gn * DDIM + g * 8];
            f32x4 v1 = *(const f32x4*)&E2[(size_t)gn * DDIM + g * 8 + 4];
            a4[0] = f2bf(v0[0]); a4[1] = f2bf(v0[1]);
            a4[2] = f2bf(v0[2]); a4[3] = f2bf(v0[3]);
            b4[0] = f2bf(v1[0]); b4[1] = f2bf(v1[1]);
            b4[2] = f2bf(v1[2]); b4[3] = f2bf(v1[3]);
        }
        *(u16x4*)&Bs[row][g * 8]     = a4;
        *(u16x4*)&Bs[row][g * 8 + 4] = b4;
    }
    __syncthreads();                 // B panel ready

    f32x4 acc[4][8];
    #pragma unroll
    for (int fm = 0; fm < 4; ++fm)
        #pragma unroll
        for (int fn = 0; fn < 8; ++fn)
            #pragma unroll
            for (int q = 0; q < 4; ++q) acc[fm][fn][q] = 0.f;

    #pragma unroll
    for (int s = 0; s < 7; ++s) {    // barrier-free k-loop
        bf16x8 af[4];
        #pragma unroll
        for (int fm = 0; fm < 4; ++fm) {
            int row = m0 + mg * 64 + fm * 16 + lr;
            af[fm] = *(const bf16x8*)&xbf[row * KPAD + s * 32 + lq * 8];
        }
        bf16x8 bfr[8];
        #pragma unroll
        for (int fn = 0; fn < 8; ++fn)
            bfr[fn] = *(const bf16x8*)&Bs[ng * 128 + fn * 16 + lr][s * 32 + lq * 8];
        #pragma unroll
        for (int fm = 0; fm < 4; ++fm)
            #pragma unroll
            for (int fn = 0; fn < 8; ++fn)
                acc[fm][fn] = __builtin_amdgcn_mfma_f32_16x16x32_bf16(
                    af[fm], bfr[fn], acc[fm][fn], 0, 0, 0);
    }

    // ---- epilogue: 16 chunks x 16 rows; one 1KB nt wave-store per out row
    for (int c = 0; c < 16; ++c) {
        __syncthreads();             // Ts free (c=0: after k-loop, Bs dead)
        if (mg == (c >> 2)) {        // owner m-group (2 waves: ng=0,1) scatters
            const int fm = c & 3;
            #pragma unroll
            for (int fn = 0; fn < 8; ++fn)
                #pragma unroll
                for (int r4 = 0; r4 < 4; ++r4)
                    Ts[lq * 4 + r4][ng * 128 + fn * 16 + lr] = acc[fm][fn][r4];
        }
        __syncthreads();
        #pragma unroll
        for (int rr = 0; rr < 2; ++rr) {
            int row = wid * 2 + rr;              // 0..15 within chunk
            f32x4 v = *(const f32x4*)&Ts[row][lane * 4];
            f32x4 o;
            #pragma unroll
            for (int j = 0; j < 4; ++j)
                o[j] = __builtin_amdgcn_rcpf(1.0f + __expf(-v[j]));
            int gm = m0 + c * 16 + row;
            int gn = n0 + lane * 4;              // NENT % 4 == 0 -> vector-safe
            if (gn < NENT)
                __builtin_nontemporal_store(o,
                    (f32x4*)&out[(size_t)gm * NENT + gn]);
        }
    }
}

extern "C" void kernel_launch(void* const* d_in, const int* in_sizes, int n_in,
                              void* d_out, int out_size, void* d_ws, size_t ws_size,
                              hipStream_t stream) {
    const int*   X  = (const int*)d_in[0];
    const float* E1 = (const float*)d_in[1];
    const float* R  = (const float*)d_in[2];
    const float* E2 = (const float*)d_in[3];
    const float* W  = (const float*)d_in[4];
    float* out = (float*)d_out;

    // workspace layout (all 16B-aligned):
    //   x_part : 50*512*200 f32 = 20,480,000 B
    //   xbf    : 512*224 u16    =    229,376 B
    //   Wt     : 200*40000 u16  = 16,000,000 B
    float* x_part = (float*)d_ws;
    u16*   xbf    = (u16*)(x_part + (size_t)SPLIT * BATCH * DDIM);
    u16*   Wt     = xbf + (size_t)BATCH * KPAD;

    transpose_w_bf16<<<KFLAT / 64, 256, 0, stream>>>(W, Wt);
    tucker_x_partial<<<dim3(BATCH / K1_BM, SPLIT), 256, 0, stream>>>(
        X, E1, R, Wt, x_part);
    reduce_x<<<dim3((BATCH * KPAD + 255) / 256), 256, 0, stream>>>(x_part, xbf);
    logits_sigmoid_mfma<<<dim3((NENT + K2_BN - 1) / K2_BN, BATCH / K2_BM),
                          512, 0, stream>>>(xbf, E2, out);
}

// Round 12
// 144.726 us; speedup vs baseline: 2.6127x; 1.0780x over previous
//
#include <hip/hip_runtime.h>
#include <cstdint>
#include <cstddef>

#define DDIM 200
#define KPAD 224          // DDIM padded to 7*32 for K2
#define BATCH 512
#define NENT 100000
#define KFLAT 40000       // 200*200 flattened (i,j)
#define SPLIT 50          // K1 split-K chunks; each = 4 i-values = 800 flat-K rows
#define CHUNK_K 800
#define K1_BM 64
#define E1P 216           // e1_s row stride u16: 432B = 16B-aligned, 2-way banks
#define BROW 232          // K2 LDS row stride in bf16 (464 B -> conflict-free b128)

typedef __attribute__((ext_vector_type(8))) short bf16x8;
typedef __attribute__((ext_vector_type(4))) float f32x4;
typedef __attribute__((ext_vector_type(4))) unsigned short u16x4;
typedef unsigned short u16;

__device__ inline u16 f2bf(float f) {
    union { float f; uint32_t u; } v; v.f = f;
    uint32_t u = v.u;
    u += 0x7FFFu + ((u >> 16) & 1u);
    return (u16)(u >> 16);
}
__device__ inline float bf2f(u16 b) {
    union { uint32_t u; float f; } v; v.u = ((uint32_t)b) << 16;
    return v.f;
}

// ---------------------------------------------------------------------------
// Kernel 0: W [40000][200] f32  ->  Wt [200][40000] bf16 (transposed, bf16).
// At BW floor: 32MB read + 16MB write ~= 7.6us.
// ---------------------------------------------------------------------------
__global__ __launch_bounds__(256) void transpose_w_bf16(
    const float* __restrict__ W, u16* __restrict__ Wt)
{
    __shared__ u16 T[DDIM][72];            // 28.8 KB, row stride 144B (16-aligned)
    const int tid = threadIdx.x;
    const int ij0 = blockIdx.x * 64;

    for (int l = tid; l < 64 * 50; l += 256) {
        int m = l & 63, c4 = l >> 6;       // m: ij within tile, c4: f32x4 group of n
        f32x4 v = *(const f32x4*)&W[(size_t)(ij0 + m) * DDIM + c4 * 4];
        #pragma unroll
        for (int q = 0; q < 4; ++q) T[c4 * 4 + q][m] = f2bf(v[q]);
    }
    __syncthreads();
    for (int l = tid; l < DDIM * 8; l += 256) {
        int n = l >> 3, g = l & 7;
        *(bf16x8*)&Wt[(size_t)n * KFLAT + ij0 + g * 8] =
            *(const bf16x8*)&T[n][g * 8];
    }
}

// ---------------------------------------------------------------------------
// Kernel 1 (R8-proven): split-K MFMA GEMM
// x[b,k] = sum_ij (r[b,i]*e1[b,j]) W[ij,k]; vectorized A-gen: base =
// s*32+(tid&3)*8 is a multiple of 8 and 200 % 8 == 0, so the 8-elem group
// never wraps a row and io is constant -> 1 div + 1 ds_read_b128 + 8 fma/cvt
// per thread/step (was 8 scalar LDS reads + 8 divisions). -31us total at R8.
// ---------------------------------------------------------------------------
__global__ __launch_bounds__(256) void tucker_x_partial(
    const int* __restrict__ X, const float* __restrict__ E1,
    const float* __restrict__ R, const u16* __restrict__ Wt,
    float* __restrict__ x_part)
{
    __shared__ u16   e1_s[K1_BM][E1P];      // bf16 e1 rows, stride 216 (432B)
    __shared__ float r_s[K1_BM][4];         // fp32 r values for chunk's 4 i's
    __shared__ u16   At[K1_BM][40];         // A tile 64x32 bf16 (pad 40)
    __shared__ u16   Bt[208][40];           // B^T tile 200x32 bf16

    const int tid = threadIdx.x;
    const int b0 = blockIdx.x * K1_BM;
    const int chunk = blockIdx.y;
    const int i0 = chunk * 4;
    const int kflat0 = chunk * CHUNK_K;

    for (int l = tid; l < K1_BM * 50; l += 256) {
        int m = l / 50, c4 = l - (l / 50) * 50;
        int subj = X[(b0 + m) * 2 + 0];
        f32x4 v = *(const f32x4*)&E1[(size_t)subj * DDIM + c4 * 4];
        u16x4 b;
        b[0] = f2bf(v[0]); b[1] = f2bf(v[1]); b[2] = f2bf(v[2]); b[3] = f2bf(v[3]);
        *(u16x4*)&e1_s[m][c4 * 4] = b;
    }
    if (tid < K1_BM * 4) {
        int m = tid >> 2, q = tid & 3;
        int rel = X[(b0 + m) * 2 + 1];
        r_s[m][q] = R[(size_t)rel * DDIM + i0 + q];
    }
    for (int l = tid; l < 8 * 40; l += 256)   // zero pad rows (n = 200..207)
        Bt[200 + l / 40][l % 40] = 0;

    const int wid = tid >> 6, lane = tid & 63;
    const int lr = lane & 15, lq = lane >> 4;

    f32x4 acc[13];
    #pragma unroll
    for (int f = 0; f < 13; ++f)
        #pragma unroll
        for (int q = 0; q < 4; ++q) acc[f][q] = 0.f;

    for (int s = 0; s < CHUNK_K / 32; ++s) {           // 25 K-steps
        __syncthreads();
        // --- stage A tile (64x32): 1 b128 read + 8 fma/cvt + 1 b128 write
        {
            int m = tid >> 2, kb = (tid & 3) * 8;
            int base = s * 32 + kb;                    // multiple of 8, 0..792
            int io = base / DDIM;                      // constant over group
            int j0 = base - io * DDIM;                 // mult of 8, <=192
            float rv = r_s[m][io];
            bf16x8 ev = *(const bf16x8*)&e1_s[m][j0];
            bf16x8 av;
            #pragma unroll
            for (int e = 0; e < 8; ++e)
                av[e] = (short)f2bf(rv * bf2f((u16)ev[e]));
            *(bf16x8*)&At[m][kb] = av;
        }
        // --- stage B^T from Wt: pure bf16x8 copies, coalesced + conflict-free
        for (int l = tid; l < DDIM * 4; l += 256) {
            int n = l >> 2, g = l & 3;
            *(bf16x8*)&Bt[n][g * 8] =
                *(const bf16x8*)&Wt[(size_t)n * KFLAT + kflat0 + s * 32 + g * 8];
        }
        __syncthreads();
        bf16x8 af = *(const bf16x8*)&At[wid * 16 + lr][lq * 8];
        #pragma unroll
        for (int f = 0; f < 13; ++f) {
            bf16x8 bfr = *(const bf16x8*)&Bt[f * 16 + lr][lq * 8];
            acc[f] = __builtin_amdgcn_mfma_f32_16x16x32_bf16(af, bfr, acc[f], 0, 0, 0);
        }
    }

    float* dst = x_part + ((size_t)chunk * BATCH + b0) * DDIM;
    #pragma unroll
    for (int f = 0; f < 13; ++f) {
        int n = f * 16 + lr;
        if (n < DDIM) {
            #pragma unroll
            for (int r4 = 0; r4 < 4; ++r4) {
                int m = wid * 16 + lq * 4 + r4;
                dst[(size_t)m * DDIM + n] = acc[f][r4];
            }
        }
    }
}

// ---------------------------------------------------------------------------
// Kernel 1b: deterministic reduction of partials -> bf16 x, padded [512][224]
// ---------------------------------------------------------------------------
__global__ __launch_bounds__(256) void reduce_x(
    const float* __restrict__ part, u16* __restrict__ xbf)
{
    int id = blockIdx.x * 256 + threadIdx.x;
    if (id < BATCH * KPAD) {
        int b = id / KPAD, c = id - (id / KPAD) * KPAD;
        float s = 0.f;
        if (c < DDIM) {
            #pragma unroll 10
            for (int ch = 0; ch < SPLIT; ++ch)
                s += part[(size_t)ch * BATCH * DDIM + b * DDIM + c];
        }
        xbf[id] = f2bf(s);
    }
}

// ---------------------------------------------------------------------------
// Kernel 2 (R12 = exact R8 revert, measured optimum): out = sigmoid(x@E2^T).
// k2's ~116us / ~2.1-2.3 TB/s is an empirical wall, invariant under: k-loop
// barriers (R1/R2), store width (R3), occupancy 2-4 blocks/CU (R6; 68%
// control R4), nt stores (R8), XCD swizzle (R9), 256B vs 1KB per-instruction
// store contiguity (R11, clean: VGPR=116, FETCH=80MB, still 123us). FETCH+
// WRITE are at the algorithmic minimum (output alone = 204.8MB). This is the
// best-measured configuration: 64-ent tiles, B panel staged once, barrier-
// free k-loop, Ts-aliases-Bs 36.9KB pool, per-wave transpose epilogue,
// 1KB-per-4-rows nt dwordx4 stores.
// ---------------------------------------------------------------------------
__global__ __launch_bounds__(512) void logits_sigmoid_mfma(
    const u16* __restrict__ xbf, const float* __restrict__ E2,
    float* __restrict__ out)
{
    __shared__ __align__(16) unsigned char lds_pool[8 * 16 * 72 * 4]; // 36,864 B
    u16   (*Bs)[BROW]   = (u16 (*)[BROW])lds_pool;     // 64 x 232 u16 = 29,696 B
    float (*Ts)[16][72] = (float (*)[16][72])lds_pool; // 8 x 16 x 72 f32

    const int tid = threadIdx.x;
    const int n0 = blockIdx.x * 64;
    const int wid = tid >> 6, lane = tid & 63;
    const int lr = lane & 15, lq = lane >> 4;

    // ---- stage whole B panel: 64 rows x 200 cols f32 -> bf16, one shot
    for (int l = tid; l < 64 * 50; l += 512) {
        int row = l / 50, c4 = l - (l / 50) * 50;
        int gn = n0 + row;
        u16x4 bb; bb[0] = 0; bb[1] = 0; bb[2] = 0; bb[3] = 0;
        if (gn < NENT) {
            f32x4 v = *(const f32x4*)&E2[(size_t)gn * DDIM + c4 * 4];
            bb[0] = f2bf(v[0]); bb[1] = f2bf(v[1]);
            bb[2] = f2bf(v[2]); bb[3] = f2bf(v[3]);
        }
        *(u16x4*)&Bs[row][c4 * 4] = bb;
    }
    {   // zero k-pad cols 200..231 (64 rows x 8 u16x4 groups = 512 tasks)
        int row = tid >> 3, g = tid & 7;
        u16x4 z; z[0] = 0; z[1] = 0; z[2] = 0; z[3] = 0;
        *(u16x4*)&Bs[row][200 + g * 4] = z;
    }
    __syncthreads();                 // B panel ready

    f32x4 acc[4][4];
    #pragma unroll
    for (int fm = 0; fm < 4; ++fm)
        #pragma unroll
        for (int fn = 0; fn < 4; ++fn)
            #pragma unroll
            for (int q = 0; q < 4; ++q) acc[fm][fn][q] = 0.f;

    #pragma unroll
    for (int s = 0; s < 7; ++s) {    // barrier-free k-loop
        bf16x8 af[4];
        #pragma unroll
        for (int fm = 0; fm < 4; ++fm) {
            int row = wid * 64 + fm * 16 + lr;
            af[fm] = *(const bf16x8*)&xbf[row * KPAD + s * 32 + lq * 8];
        }
        bf16x8 bfr[4];
        #pragma unroll
        for (int fn = 0; fn < 4; ++fn)
            bfr[fn] = *(const bf16x8*)&Bs[fn * 16 + lr][s * 32 + lq * 8];
        #pragma unroll
        for (int fm = 0; fm < 4; ++fm)
            #pragma unroll
            for (int fn = 0; fn < 4; ++fn)
                acc[fm][fn] = __builtin_amdgcn_mfma_f32_16x16x32_bf16(
                    af[fm], bfr[fn], acc[fm][fn], 0, 0, 0);
    }

    __syncthreads();                 // Bs dead everywhere -> Ts may reuse LDS

    // ---- wide-store epilogue: per-wave LDS transpose, no inter-wave sync
    #pragma unroll
    for (int fm = 0; fm < 4; ++fm) {
        int gm0 = wid * 64 + fm * 16;
        // scatter this wave's 16x64 sub-tile into its private slice
        #pragma unroll
        for (int fn = 0; fn < 4; ++fn)
            #pragma unroll
            for (int r4 = 0; r4 < 4; ++r4)
                Ts[wid][lq * 4 + r4][fn * 16 + lr] = acc[fm][fn][r4];
        // read back row-major: lane -> (row, 4 consecutive cols)
        #pragma unroll
        for (int rr = 0; rr < 4; ++rr) {
            int row = rr * 4 + lq;           // 0..15
            f32x4 v = *(const f32x4*)&Ts[wid][row][lr * 4];
            f32x4 o;
            #pragma unroll
            for (int q = 0; q < 4; ++q)
                o[q] = __builtin_amdgcn_rcpf(1.0f + __expf(-v[q]));
            int gn = n0 + lr * 4;            // NENT % 4 == 0 -> vector-safe guard
            if (gn < NENT)
                __builtin_nontemporal_store(o,
                    (f32x4*)&out[(size_t)(gm0 + row) * NENT + gn]);
        }
    }
}

extern "C" void kernel_launch(void* const* d_in, const int* in_sizes, int n_in,
                              void* d_out, int out_size, void* d_ws, size_t ws_size,
                              hipStream_t stream) {
    const int*   X  = (const int*)d_in[0];
    const float* E1 = (const float*)d_in[1];
    const float* R  = (const float*)d_in[2];
    const float* E2 = (const float*)d_in[3];
    const float* W  = (const float*)d_in[4];
    float* out = (float*)d_out;

    // workspace layout (all 16B-aligned):
    //   x_part : 50*512*200 f32 = 20,480,000 B
    //   xbf    : 512*224 u16    =    229,376 B
    //   Wt     : 200*40000 u16  = 16,000,000 B
    float* x_part = (float*)d_ws;
    u16*   xbf    = (u16*)(x_part + (size_t)SPLIT * BATCH * DDIM);
    u16*   Wt     = xbf + (size_t)BATCH * KPAD;

    transpose_w_bf16<<<KFLAT / 64, 256, 0, stream>>>(W, Wt);
    tucker_x_partial<<<dim3(BATCH / K1_BM, SPLIT), 256, 0, stream>>>(
        X, E1, R, Wt, x_part);
    reduce_x<<<dim3((BATCH * KPAD + 255) / 256), 256, 0, stream>>>(x_part, xbf);
    logits_sigmoid_mfma<<<dim3((NENT + 63) / 64), 512, 0, stream>>>(xbf, E2, out);
}